// Round 1
// baseline (133.006 us; speedup 1.0000x reference)
//
#include <hip/hip_runtime.h>
#include <hip/hip_bf16.h>

// y = relu(x @ W + b); x [65536,1024] f32, W [1024,84] f32, b [84] f32.
// Strategy: bf16 MFMA (16x16x32), N padded 84->96 (6 n-tiles), one wave per
// 16-row output strip, A-fragments straight from global (exact once-only
// coverage of x), W pre-transposed to bf16 [96][1024] in d_ws (L2-resident).

typedef __attribute__((ext_vector_type(4))) float f32x4;
typedef __attribute__((ext_vector_type(8))) short bf16x8;

#define FEAT 1024
#define NOUT 84
#define NPAD 96
#define BATCH 65536

__device__ __forceinline__ unsigned short f2bf(float f) {
  __hip_bfloat16 h = __float2bfloat16(f);
  union { __hip_bfloat16 h; unsigned short u; } c;
  c.h = h;
  return c.u;
}

// Convert W [1024][84] f32 -> Wt [96][1024] bf16 (cols 84..95 zero),
// and b [84] f32 -> bpad [96] f32 (zero-padded).
__global__ __launch_bounds__(256) void prep_kernel(
    const float* __restrict__ W, const float* __restrict__ b,
    unsigned short* __restrict__ Wt, float* __restrict__ bpad) {
  int idx = blockIdx.x * 256 + threadIdx.x;  // 0 .. 98303 (= 96*1024)
  int n = idx >> 10;                         // output column
  int k = idx & 1023;                        // feature index
  unsigned short v = 0;
  if (n < NOUT) v = f2bf(W[(size_t)k * NOUT + n]);
  Wt[idx] = v;                               // Wt[n][k]
  if (idx < NPAD) bpad[idx] = (idx < NOUT) ? b[idx] : 0.0f;
}

__global__ __launch_bounds__(256) void gemm_kernel(
    const float* __restrict__ x, const unsigned short* __restrict__ Wt,
    const float* __restrict__ bpad, float* __restrict__ out) {
  const int wave = threadIdx.x >> 6;
  const int lane = threadIdx.x & 63;
  const int r = lane & 15;   // A: row-in-tile; B: col-in-tile; D: col-in-tile
  const int g = lane >> 4;   // k-group (A/B), row-group (D)
  const int row0 = (blockIdx.x * 4 + wave) * 16;

  // A fragment source: lane reads x[row0+r][ks*32 + g*8 .. +7]
  const float* xp = x + (size_t)(row0 + r) * FEAT + g * 8;
  // B fragment source: lane reads Wt[ntile*16 + r][ks*32 + g*8 .. +7]
  const unsigned short* wp = Wt + r * FEAT + g * 8;

  f32x4 acc[6];
#pragma unroll
  for (int n = 0; n < 6; ++n) acc[n] = (f32x4){0.f, 0.f, 0.f, 0.f};

#pragma unroll 4
  for (int ks = 0; ks < 32; ++ks) {
    f32x4 a0 = *(const f32x4*)(xp + ks * 32);
    f32x4 a1 = *(const f32x4*)(xp + ks * 32 + 4);
    bf16x8 af;
    af[0] = (short)f2bf(a0[0]);
    af[1] = (short)f2bf(a0[1]);
    af[2] = (short)f2bf(a0[2]);
    af[3] = (short)f2bf(a0[3]);
    af[4] = (short)f2bf(a1[0]);
    af[5] = (short)f2bf(a1[1]);
    af[6] = (short)f2bf(a1[2]);
    af[7] = (short)f2bf(a1[3]);
#pragma unroll
    for (int n = 0; n < 6; ++n) {
      bf16x8 bf = *(const bf16x8*)(wp + ks * 32 + n * 16 * FEAT);
      acc[n] = __builtin_amdgcn_mfma_f32_16x16x32_bf16(af, bf, acc[n], 0, 0, 0);
    }
  }

  // Epilogue: D layout col = lane&15, row = (lane>>4)*4 + j.
#pragma unroll
  for (int n = 0; n < 6; ++n) {
    int col = n * 16 + r;
    if (col < NOUT) {
      float bias = bpad[col];
#pragma unroll
      for (int j = 0; j < 4; ++j) {
        float v = acc[n][j] + bias;
        v = v > 0.f ? v : 0.f;
        out[(size_t)(row0 + g * 4 + j) * NOUT + col] = v;
      }
    }
  }
}

extern "C" void kernel_launch(void* const* d_in, const int* in_sizes, int n_in,
                              void* d_out, int out_size, void* d_ws, size_t ws_size,
                              hipStream_t stream) {
  const float* x = (const float*)d_in[0];
  const float* W = (const float*)d_in[1];
  const float* b = (const float*)d_in[2];
  float* out = (float*)d_out;

  unsigned short* Wt = (unsigned short*)d_ws;                       // 96*1024 bf16
  float* bpad = (float*)((char*)d_ws + (size_t)NPAD * FEAT * 2);    // 96 f32

  prep_kernel<<<(NPAD * FEAT) / 256, 256, 0, stream>>>(W, b, Wt, bpad);
  gemm_kernel<<<BATCH / 64, 256, 0, stream>>>(x, Wt, bpad, out);
}

// Round 2
// 63.987 us; speedup vs baseline: 2.0786x; 2.0786x over previous
//
#include <hip/hip_runtime.h>
#include <hip/hip_bf16.h>

// y = relu(x @ W + b); x [65536,1024] f32, W [1024,84] f32, b [84] f32.
// R2: bf16 MFMA 16x16x32; Wt (bf16, [96][1024]) staged into LDS in K-chunks
// of 128 (24KB), double-buffered, via global_load_lds w=16 with XOR-swizzled
// source (linear LDS dest). A-fragments stream from global x once-only.

typedef __attribute__((ext_vector_type(4))) float f32x4;
typedef __attribute__((ext_vector_type(8))) short bf16x8;

#define FEAT 1024
#define NOUT 84
#define NPAD 96
#define BATCH 65536
#define CHUNK 128                    // k-elems per LDS chunk
#define NCHUNK (FEAT / CHUNK)        // 8
#define ROWB (CHUNK * 2)             // 256 bytes per LDS row
#define CHUNK_BYTES (NPAD * ROWB)    // 24576

typedef __attribute__((address_space(3))) unsigned int lds_uint;
typedef __attribute__((address_space(1))) const unsigned int glb_uint;

__device__ __forceinline__ unsigned short f2bf(float f) {
  union { __hip_bfloat16 h; unsigned short u; } c;
  c.h = __float2bfloat16(f);
  return c.u;
}

// W [1024][84] f32 -> Wt [96][1024] bf16 (rows 84..95 zero); b -> bpad[96].
__global__ __launch_bounds__(256) void prep_kernel(
    const float* __restrict__ W, const float* __restrict__ b,
    unsigned short* __restrict__ Wt, float* __restrict__ bpad) {
  int idx = blockIdx.x * 256 + threadIdx.x;  // 0 .. 98303
  int n = idx >> 10;
  int k = idx & 1023;
  unsigned short v = 0;
  if (n < NOUT) v = f2bf(W[(size_t)k * NOUT + n]);
  Wt[idx] = v;
  if (idx < NPAD) bpad[idx] = (idx < NOUT) ? b[idx] : 0.0f;
}

__global__ __launch_bounds__(512) void gemm_kernel(
    const float* __restrict__ x, const unsigned short* __restrict__ Wt,
    const float* __restrict__ bpad, float* __restrict__ out) {
  __shared__ __align__(16) unsigned char smem[2 * CHUNK_BYTES];  // 48 KB

  const int tid = threadIdx.x;
  const int wave = tid >> 6;
  const int lane = tid & 63;
  const int r = lane & 15;   // A row-in-tile / B col-in-tile / D col
  const int g = lane >> 4;   // k-group / D row-group
  const int row0 = (blockIdx.x * 8 + wave) * 16;
  const int rsw = (r & 7) << 4;  // XOR swizzle bits 4..6

  // A source: lane reads x[row0+r][c*128 + kk*32 + g*8 .. +7]
  const float* xp = x + (size_t)(row0 + r) * FEAT + g * 8;

  f32x4 acc[6];
#pragma unroll
  for (int t = 0; t < 6; ++t) acc[t] = (f32x4){0.f, 0.f, 0.f, 0.f};

  // Stage chunk c of Wt into LDS buffer `buf`. Linear LDS dest (HW: wave-
  // uniform base + lane*16); source address carries the inverse swizzle.
  auto stage = [&](int c, int buf) {
#pragma unroll
    for (int s = 0; s < 3; ++s) {
      int d = s * 8192 + wave * 1024 + lane * 16;  // linear byte in chunk
      int n = d >> 8;                              // LDS row (= Wt row)
      int cb = d & 255;                            // byte-col in chunk row
      const unsigned char* src = (const unsigned char*)Wt +
          (size_t)n * (FEAT * 2) + c * ROWB + (cb ^ ((n & 7) << 4));
      unsigned char* dst = &smem[buf * CHUNK_BYTES + s * 8192 + wave * 1024];
      __builtin_amdgcn_global_load_lds((glb_uint*)src, (lds_uint*)dst, 16, 0, 0);
    }
  };

  stage(0, 0);
  __syncthreads();

  for (int c = 0; c < NCHUNK; ++c) {
    if (c + 1 < NCHUNK) stage(c + 1, (c + 1) & 1);  // prefetch next chunk
    const unsigned char* bb = &smem[(c & 1) * CHUNK_BYTES];
#pragma unroll
    for (int kk = 0; kk < 4; ++kk) {
      const float* xk = xp + c * CHUNK + kk * 32;
      f32x4 a0 = *(const f32x4*)(xk);
      f32x4 a1 = *(const f32x4*)(xk + 4);
      bf16x8 af;
      af[0] = (short)f2bf(a0[0]);
      af[1] = (short)f2bf(a0[1]);
      af[2] = (short)f2bf(a0[2]);
      af[3] = (short)f2bf(a0[3]);
      af[4] = (short)f2bf(a1[0]);
      af[5] = (short)f2bf(a1[1]);
      af[6] = (short)f2bf(a1[2]);
      af[7] = (short)f2bf(a1[3]);
#pragma unroll
      for (int t = 0; t < 6; ++t) {
        int addr = (t * 16 + r) * ROWB + ((kk * 64 + g * 16) ^ rsw);
        bf16x8 bf = *(const bf16x8*)(bb + addr);
        acc[t] = __builtin_amdgcn_mfma_f32_16x16x32_bf16(af, bf, acc[t], 0, 0, 0);
      }
    }
    __syncthreads();
  }

  // Epilogue: D layout col = lane&15, row = (lane>>4)*4 + j.
#pragma unroll
  for (int t = 0; t < 6; ++t) {
    int col = t * 16 + r;
    if (col < NOUT) {
      float bias = bpad[col];
#pragma unroll
      for (int j = 0; j < 4; ++j) {
        float v = acc[t][j] + bias;
        v = v > 0.f ? v : 0.f;
        out[(size_t)(row0 + g * 4 + j) * NOUT + col] = v;
      }
    }
  }
}

extern "C" void kernel_launch(void* const* d_in, const int* in_sizes, int n_in,
                              void* d_out, int out_size, void* d_ws, size_t ws_size,
                              hipStream_t stream) {
  const float* x = (const float*)d_in[0];
  const float* W = (const float*)d_in[1];
  const float* b = (const float*)d_in[2];
  float* out = (float*)d_out;

  unsigned short* Wt = (unsigned short*)d_ws;                    // 96*1024 bf16
  float* bpad = (float*)((char*)d_ws + (size_t)NPAD * FEAT * 2); // 96 f32

  prep_kernel<<<(NPAD * FEAT) / 256, 256, 0, stream>>>(W, b, Wt, bpad);
  gemm_kernel<<<BATCH / 128, 512, 0, stream>>>(x, Wt, bpad, out);
}

// Round 3
// 59.392 us; speedup vs baseline: 2.2395x; 1.0774x over previous
//
#include <hip/hip_runtime.h>
#include <hip/hip_bf16.h>

// y = relu(x @ W + b); x [65536,1024] f32, W [1024,84] f32, b [84] f32.
// R3: bf16 MFMA 16x16x32; Wt bf16 [96][1024] staged to LDS in K-chunks of 128
// (24KB, double-buffered, global_load_lds w=16, XOR-swizzled source).
// New: register-level x prefetch one chunk ahead (T14) + counted vmcnt(8)
// with raw s_barrier (T4) so x-prefetch loads stay in flight across barriers.

typedef __attribute__((ext_vector_type(4))) float f32x4;
typedef __attribute__((ext_vector_type(8))) short bf16x8;

#define FEAT 1024
#define NOUT 84
#define NPAD 96
#define BATCH 65536
#define CHUNK 128
#define NCHUNK (FEAT / CHUNK)        // 8
#define ROWB (CHUNK * 2)             // 256 B per LDS row
#define CHUNK_BYTES (NPAD * ROWB)    // 24576

typedef __attribute__((address_space(3))) unsigned int lds_uint;
typedef __attribute__((address_space(1))) const unsigned int glb_uint;

__device__ __forceinline__ unsigned short f2bf(float f) {
  union { __hip_bfloat16 h; unsigned short u; } c;
  c.h = __float2bfloat16(f);
  return c.u;
}

__global__ __launch_bounds__(256) void prep_kernel(
    const float* __restrict__ W, const float* __restrict__ b,
    unsigned short* __restrict__ Wt, float* __restrict__ bpad) {
  int idx = blockIdx.x * 256 + threadIdx.x;  // 0 .. 98303
  int n = idx >> 10;
  int k = idx & 1023;
  unsigned short v = 0;
  if (n < NOUT) v = f2bf(W[(size_t)k * NOUT + n]);
  Wt[idx] = v;
  if (idx < NPAD) bpad[idx] = (idx < NOUT) ? b[idx] : 0.0f;
}

__global__ __launch_bounds__(512, 4) void gemm_kernel(
    const float* __restrict__ x, const unsigned short* __restrict__ Wt,
    const float* __restrict__ bpad, float* __restrict__ out) {
  __shared__ __align__(16) unsigned char smem[2 * CHUNK_BYTES];  // 48 KB

  const int tid = threadIdx.x;
  const int wave = tid >> 6;
  const int lane = tid & 63;
  const int r = lane & 15;   // A row-in-tile / B col-in-tile / D col
  const int g = lane >> 4;   // k-group / D row-group
  const int row0 = (blockIdx.x * 8 + wave) * 16;
  const int rsw = (r & 7) << 4;

  const float* xp = x + (size_t)(row0 + r) * FEAT + g * 8;

  f32x4 acc[6];
#pragma unroll
  for (int t = 0; t < 6; ++t) acc[t] = (f32x4){0.f, 0.f, 0.f, 0.f};

  // Stage chunk c of Wt into LDS buffer. Linear LDS dest; source address
  // carries the inverse XOR swizzle (rule #21: both-sides-or-neither).
  auto stage = [&](int c, int buf) {
#pragma unroll
    for (int s = 0; s < 3; ++s) {
      int d = s * 8192 + wave * 1024 + lane * 16;
      int n = d >> 8;
      int cb = d & 255;
      const unsigned char* src = (const unsigned char*)Wt +
          (size_t)n * (FEAT * 2) + c * ROWB + (cb ^ ((n & 7) << 4));
      unsigned char* dst = &smem[buf * CHUNK_BYTES + s * 8192 + wave * 1024];
      __builtin_amdgcn_global_load_lds((glb_uint*)src, (lds_uint*)dst, 16, 0, 0);
    }
  };

  f32x4 xcur[8], xnxt[8];

  // Prologue: stage chunk 0 + load chunk-0 x into regs; full drain once.
  stage(0, 0);
#pragma unroll
  for (int i = 0; i < 8; ++i)
    xcur[i] = *(const f32x4*)(xp + (i >> 1) * 32 + (i & 1) * 4);
  __syncthreads();

#pragma unroll
  for (int c = 0; c < NCHUNK; ++c) {
    if (c + 1 < NCHUNK) {
      // Stage FIRST (oldest in vmcnt FIFO), then x prefetch; pin the order.
      stage(c + 1, (c + 1) & 1);
      __builtin_amdgcn_sched_barrier(0);
#pragma unroll
      for (int i = 0; i < 8; ++i)
        xnxt[i] = *(const f32x4*)(xp + (c + 1) * CHUNK + (i >> 1) * 32 + (i & 1) * 4);
      __builtin_amdgcn_sched_barrier(0);
    }

    const unsigned char* bb = &smem[(c & 1) * CHUNK_BYTES];
#pragma unroll
    for (int kk = 0; kk < 4; ++kk) {
      f32x4 a0 = xcur[kk * 2];
      f32x4 a1 = xcur[kk * 2 + 1];
      bf16x8 af;
      af[0] = (short)f2bf(a0[0]);
      af[1] = (short)f2bf(a0[1]);
      af[2] = (short)f2bf(a0[2]);
      af[3] = (short)f2bf(a0[3]);
      af[4] = (short)f2bf(a1[0]);
      af[5] = (short)f2bf(a1[1]);
      af[6] = (short)f2bf(a1[2]);
      af[7] = (short)f2bf(a1[3]);
#pragma unroll
      for (int t = 0; t < 6; ++t) {
        int addr = (t * 16 + r) * ROWB + ((kk * 64 + g * 16) ^ rsw);
        bf16x8 bf = *(const bf16x8*)(bb + addr);
        acc[t] = __builtin_amdgcn_mfma_f32_16x16x32_bf16(af, bf, acc[t], 0, 0, 0);
      }
    }

    if (c + 1 < NCHUNK) {
      // Stage's 3 loads are the 11-deep FIFO's oldest: vmcnt(8) ensures the
      // LDS staging landed while the 8 x-prefetches stay in flight.
      asm volatile("s_waitcnt vmcnt(8)" ::: "memory");
      __builtin_amdgcn_s_barrier();
      asm volatile("" ::: "memory");
#pragma unroll
      for (int i = 0; i < 8; ++i) xcur[i] = xnxt[i];  // free after full unroll
    }
  }

  // Epilogue: D layout col = lane&15, row = (lane>>4)*4 + j.
#pragma unroll
  for (int t = 0; t < 6; ++t) {
    int col = t * 16 + r;
    if (col < NOUT) {
      float bias = bpad[col];
#pragma unroll
      for (int j = 0; j < 4; ++j) {
        float v = acc[t][j] + bias;
        v = v > 0.f ? v : 0.f;
        out[(size_t)(row0 + g * 4 + j) * NOUT + col] = v;
      }
    }
  }
}

extern "C" void kernel_launch(void* const* d_in, const int* in_sizes, int n_in,
                              void* d_out, int out_size, void* d_ws, size_t ws_size,
                              hipStream_t stream) {
  const float* x = (const float*)d_in[0];
  const float* W = (const float*)d_in[1];
  const float* b = (const float*)d_in[2];
  float* out = (float*)d_out;

  unsigned short* Wt = (unsigned short*)d_ws;                    // 96*1024 bf16
  float* bpad = (float*)((char*)d_ws + (size_t)NPAD * FEAT * 2); // 96 f32

  prep_kernel<<<(NPAD * FEAT) / 256, 256, 0, stream>>>(W, b, Wt, bpad);
  gemm_kernel<<<BATCH / 128, 512, 0, stream>>>(x, Wt, bpad, out);
}

// Round 4
// 57.370 us; speedup vs baseline: 2.3184x; 1.0352x over previous
//
#include <hip/hip_runtime.h>
#include <hip/hip_bf16.h>

// y = relu(x @ W + b); x [65536,1024] f32, W [1024,84] f32, b [84] f32.
// R4: as R3 (bf16 MFMA, LDS-staged Wt double-buffered via global_load_lds,
// reg-level x prefetch, counted vmcnt(8) barriers) + coalesced epilogue:
// stage the block's 128x84 f32 output in LDS, stream out as linear dwordx4.

typedef __attribute__((ext_vector_type(4))) float f32x4;
typedef __attribute__((ext_vector_type(8))) short bf16x8;

#define FEAT 1024
#define NOUT 84
#define NPAD 96
#define BATCH 65536
#define CHUNK 128
#define NCHUNK (FEAT / CHUNK)        // 8
#define ROWB (CHUNK * 2)             // 256 B per LDS row
#define CHUNK_BYTES (NPAD * ROWB)    // 24576

typedef __attribute__((address_space(3))) unsigned int lds_uint;
typedef __attribute__((address_space(1))) const unsigned int glb_uint;

__device__ __forceinline__ unsigned short f2bf(float f) {
  union { __hip_bfloat16 h; unsigned short u; } c;
  c.h = __float2bfloat16(f);
  return c.u;
}

__global__ __launch_bounds__(256) void prep_kernel(
    const float* __restrict__ W, const float* __restrict__ b,
    unsigned short* __restrict__ Wt, float* __restrict__ bpad) {
  int idx = blockIdx.x * 256 + threadIdx.x;  // 0 .. 98303
  int n = idx >> 10;
  int k = idx & 1023;
  unsigned short v = 0;
  if (n < NOUT) v = f2bf(W[(size_t)k * NOUT + n]);
  Wt[idx] = v;
  if (idx < NPAD) bpad[idx] = (idx < NOUT) ? b[idx] : 0.0f;
}

__global__ __launch_bounds__(512, 4) void gemm_kernel(
    const float* __restrict__ x, const unsigned short* __restrict__ Wt,
    const float* __restrict__ bpad, float* __restrict__ out) {
  __shared__ __align__(16) unsigned char smem[2 * CHUNK_BYTES];  // 48 KB

  const int tid = threadIdx.x;
  const int wave = tid >> 6;
  const int lane = tid & 63;
  const int r = lane & 15;   // A row-in-tile / B col-in-tile / D col
  const int g = lane >> 4;   // k-group / D row-group
  const int row0 = (blockIdx.x * 8 + wave) * 16;
  const int rsw = (r & 7) << 4;

  const float* xp = x + (size_t)(row0 + r) * FEAT + g * 8;

  f32x4 acc[6];
#pragma unroll
  for (int t = 0; t < 6; ++t) acc[t] = (f32x4){0.f, 0.f, 0.f, 0.f};

  // Stage chunk c of Wt into LDS buffer. Linear LDS dest; source address
  // carries the inverse XOR swizzle (rule #21: both-sides-or-neither).
  auto stage = [&](int c, int buf) {
#pragma unroll
    for (int s = 0; s < 3; ++s) {
      int d = s * 8192 + wave * 1024 + lane * 16;
      int n = d >> 8;
      int cb = d & 255;
      const unsigned char* src = (const unsigned char*)Wt +
          (size_t)n * (FEAT * 2) + c * ROWB + (cb ^ ((n & 7) << 4));
      unsigned char* dst = &smem[buf * CHUNK_BYTES + s * 8192 + wave * 1024];
      __builtin_amdgcn_global_load_lds((glb_uint*)src, (lds_uint*)dst, 16, 0, 0);
    }
  };

  f32x4 xcur[8], xnxt[8];

  stage(0, 0);
#pragma unroll
  for (int i = 0; i < 8; ++i)
    xcur[i] = *(const f32x4*)(xp + (i >> 1) * 32 + (i & 1) * 4);
  __syncthreads();

#pragma unroll
  for (int c = 0; c < NCHUNK; ++c) {
    if (c + 1 < NCHUNK) {
      stage(c + 1, (c + 1) & 1);
      __builtin_amdgcn_sched_barrier(0);
#pragma unroll
      for (int i = 0; i < 8; ++i)
        xnxt[i] = *(const f32x4*)(xp + (c + 1) * CHUNK + (i >> 1) * 32 + (i & 1) * 4);
      __builtin_amdgcn_sched_barrier(0);
    }

    const unsigned char* bb = &smem[(c & 1) * CHUNK_BYTES];
#pragma unroll
    for (int kk = 0; kk < 4; ++kk) {
      f32x4 a0 = xcur[kk * 2];
      f32x4 a1 = xcur[kk * 2 + 1];
      bf16x8 af;
      af[0] = (short)f2bf(a0[0]);
      af[1] = (short)f2bf(a0[1]);
      af[2] = (short)f2bf(a0[2]);
      af[3] = (short)f2bf(a0[3]);
      af[4] = (short)f2bf(a1[0]);
      af[5] = (short)f2bf(a1[1]);
      af[6] = (short)f2bf(a1[2]);
      af[7] = (short)f2bf(a1[3]);
#pragma unroll
      for (int t = 0; t < 6; ++t) {
        int addr = (t * 16 + r) * ROWB + ((kk * 64 + g * 16) ^ rsw);
        bf16x8 bf = *(const bf16x8*)(bb + addr);
        acc[t] = __builtin_amdgcn_mfma_f32_16x16x32_bf16(af, bf, acc[t], 0, 0, 0);
      }
    }

    if (c + 1 < NCHUNK) {
      // vmcnt(8): the 3 stage loads (oldest in FIFO) have landed; the 8
      // x-prefetch loads stay in flight across the barrier.
      asm volatile("s_waitcnt vmcnt(8)" ::: "memory");
      __builtin_amdgcn_s_barrier();
      asm volatile("" ::: "memory");
#pragma unroll
      for (int i = 0; i < 8; ++i) xcur[i] = xnxt[i];  // renamed away (unrolled)
    }
  }

  // Epilogue: stage bias+ReLU'd output in LDS ([128][84] f32 = 43008 B),
  // then stream the block's contiguous 43008-B span with coalesced dwordx4.
  __syncthreads();  // all ds_reads of the last chunk complete
  float* osm = (float*)smem;
#pragma unroll
  for (int t = 0; t < 6; ++t) {
    int col = t * 16 + r;
    if (col < NOUT) {
      float bias = bpad[col];
#pragma unroll
      for (int j = 0; j < 4; ++j) {
        float v = acc[t][j] + bias;
        v = v > 0.f ? v : 0.f;
        osm[(wave * 16 + g * 4 + j) * NOUT + col] = v;
      }
    }
  }
  __syncthreads();

  f32x4* op = (f32x4*)(out + (size_t)blockIdx.x * 128 * NOUT);
  const f32x4* sp = (const f32x4*)osm;
#pragma unroll
  for (int i = 0; i < 6; ++i) {
    int idx = i * 512 + tid;
    if (idx < (128 * NOUT) / 4) op[idx] = sp[idx];
  }
}

extern "C" void kernel_launch(void* const* d_in, const int* in_sizes, int n_in,
                              void* d_out, int out_size, void* d_ws, size_t ws_size,
                              hipStream_t stream) {
  const float* x = (const float*)d_in[0];
  const float* W = (const float*)d_in[1];
  const float* b = (const float*)d_in[2];
  float* out = (float*)d_out;

  unsigned short* Wt = (unsigned short*)d_ws;                    // 96*1024 bf16
  float* bpad = (float*)((char*)d_ws + (size_t)NPAD * FEAT * 2); // 96 f32

  prep_kernel<<<(NPAD * FEAT) / 256, 256, 0, stream>>>(W, b, Wt, bpad);
  gemm_kernel<<<BATCH / 128, 512, 0, stream>>>(x, Wt, bpad, out);
}